// Round 5
// baseline (146.262 us; speedup 1.0000x reference)
//
#include <hip/hip_runtime.h>
#include <math.h>

#define NGRAPH 256
#define NPG 256
#define HF 128
#define EPG 4096      // real edges per graph (global arrays)
#define EPG2 4352     // CSR slots incl one self-edge per node
#define FSTR 132      // f32 row stride in tbufF (aliases hpair)
#define PSTR 136      // short row stride in hpair (16B-aligned rows)

typedef __attribute__((ext_vector_type(8))) short bf16x8;
typedef __attribute__((ext_vector_type(4))) float f32x4;

static __device__ __forceinline__ unsigned bcu(float f){ return __builtin_bit_cast(unsigned, f); }
static __device__ __forceinline__ float bcf(unsigned u){ return __builtin_bit_cast(float, u); }
static __device__ __forceinline__ unsigned rtn16(float f){
  unsigned u = bcu(f);
  return (u + 0x7FFFu + ((u >> 16) & 1u)) >> 16;
}

// ---------------- W transpose + split to bf16 hi/lo: Wt[n][k] ----------------
__global__ __launch_bounds__(256) void prep_wt(const float* __restrict__ W1,
                                               const float* __restrict__ W2,
                                               const float* __restrict__ W3,
                                               short* __restrict__ Wt) {
  int idx = blockIdx.x * 256 + threadIdx.x;           // 0 .. 3*16384
  int L = idx >> 14, r = idx & 16383;
  int k = r >> 7, n = r & 127;
  const float* W = (L == 0) ? W1 : (L == 1) ? W2 : W3;
  float w = W[k*128 + n];
  unsigned hi = rtn16(w);
  float lo = w - bcf(hi << 16);
  short* Whi = Wt + (size_t)L * 2 * 16384;
  short* Wlo = Whi + 16384;
  Whi[n*128 + k] = (short)hi;
  Wlo[n*128 + k] = (short)(bcu(lo) >> 16);
}

// sort compare-exchange step (descending key, ascending idx on ties)
#define BSTEP(OK, OI, KKc, Jc) do { \
  bool iLess = ((tid & (Jc)) == 0); \
  bool descR = ((tid & (KKc)) == 0); \
  bool myFirst = (kf > (OK)) || (kf == (OK) && ki < (OI)); \
  bool keep = (iLess == descR) ? myFirst : !myFirst; \
  if (!keep) { kf = (OK); ki = (OI); } \
} while (0)

// ---------------- whole network, one block per graph ----------------
__global__ __launch_bounds__(1024) void fused_net(
    const float* __restrict__ x,
    const int* __restrict__ srcI, const int* __restrict__ dstI,
    const short* __restrict__ WtAll,
    const float* __restrict__ b1, const float* __restrict__ Ws1, const float* __restrict__ bs1,
    const float* __restrict__ b2, const float* __restrict__ Ws2, const float* __restrict__ bs2,
    const float* __restrict__ b3, const float* __restrict__ Ws3, const float* __restrict__ bs3,
    const float* __restrict__ Wl1, const float* __restrict__ bl1,
    const float* __restrict__ Wl2, const float* __restrict__ bl2,
    const float* __restrict__ Wl3, const float* __restrict__ bl3,
    float* __restrict__ out)
{
  __shared__ __align__(16) short hpair[2][NPG*PSTR];   // 139264 B; aliased by tbufF
  __shared__ unsigned char colS[EPG2 + 8];             // CSR col (src local idx), by dst, incl self
  __shared__ unsigned short rloc[NPG+2];
  __shared__ unsigned mbits[8];                        // survivor bitmask
  __shared__ float dinv[NPG];
  __shared__ __align__(16) float bvec[HF];
  __shared__ __align__(16) float wsv[HF];
  __shared__ float score[NPG];
  __shared__ float tscale[NPG];                        // tq scratch / tanh scale
  __shared__ float nmf[NPG];
  __shared__ float skey[NPG];
  __shared__ int   sidx[NPG];
  __shared__ __align__(16) float red[1024];            // partials / readout / MLP scratch
  __shared__ float zacc[2*HF];

  float* tbufF = (float*)&hpair[0][0];                 // [node][FSTR] f32 (G rows), alias
  short* hp0 = &hpair[0][0];
  short* hp1 = &hpair[1][0];
  int* cntA = (int*)skey;                              // CSR-build-only aliases
  int* curA = sidx;

  int tid = threadIdx.x;
  int g = blockIdx.x;
  size_t nbase = (size_t)g * NPG;
  int lane = tid & 63, wid = tid >> 6;
  int v = tid >> 2, fq = tid & 3, cb = fq * 4;

  // ---- stage x into bf16 hi/lo pair ----
  const float4* X4 = (const float4*)(x + nbase*HF);
  #pragma unroll
  for (int i = 0; i < 8; ++i) {
    int f4 = tid + i*1024;
    int r = f4 >> 5, kq = f4 & 31;
    float4 val = X4[f4];
    unsigned rx = rtn16(val.x), ry = rtn16(val.y), rz = rtn16(val.z), rw = rtn16(val.w);
    uint2 ph; ph.x = rx | (ry << 16); ph.y = rz | (rw << 16);
    float lx = val.x - bcf(rx << 16), ly = val.y - bcf(ry << 16);
    float lz = val.z - bcf(rz << 16), lw = val.w - bcf(rw << 16);
    uint2 pl; pl.x = (bcu(lx) >> 16) | (bcu(ly) & 0xFFFF0000u);
    pl.y = (bcu(lz) >> 16) | (bcu(lw) & 0xFFFF0000u);
    *(uint2*)&hp0[r*PSTR + kq*4] = ph;
    *(uint2*)&hp1[r*PSTR + kq*4] = pl;
  }

  // ---- CSR build in LDS (counting sort by dst, +1 self slot per node) ----
  if (tid < NPG) cntA[tid] = 1;                        // self-edge reserved
  if (tid < 8) mbits[tid] = 0xFFFFFFFFu;
  __syncthreads();
  int nb = g * NPG;
  int dloc[4], sloc[4];
  #pragma unroll
  for (int it = 0; it < 4; ++it) {
    int e = g*EPG + tid + it*1024;
    dloc[it] = dstI[e] - nb;
    sloc[it] = srcI[e] - nb;
    atomicAdd(&cntA[dloc[it]], 1);
  }
  __syncthreads();
  if (tid < NPG) sidx[tid] = cntA[tid];
  __syncthreads();
  for (int off = 1; off < NPG; off <<= 1) {
    int t = (tid >= off && tid < NPG) ? sidx[tid-off] : 0;
    __syncthreads();
    if (tid < NPG) sidx[tid] += t;
    __syncthreads();
  }
  int excl_ = 0;
  if (tid < NPG) excl_ = sidx[tid] - cntA[tid];
  __syncthreads();
  if (tid < NPG) { rloc[tid] = (unsigned short)excl_; curA[tid] = excl_; }
  if (tid == 0) rloc[NPG] = (unsigned short)EPG2;
  __syncthreads();
  #pragma unroll
  for (int it = 0; it < 4; ++it) {
    int slot = atomicAdd(&curA[dloc[it]], 1);
    colS[slot] = (unsigned char)sloc[it];
  }
  if (tid < NPG) colS[rloc[tid+1] - 1] = (unsigned char)tid;  // self in last slot

  // ---- 3 GCN+SAGPool layers ----
  #pragma unroll 1
  for (int L = 0; L < 3; ++L) {
    const short* Whi = WtAll + (size_t)L * 2 * 16384;
    const short* Wlo = Whi + 16384;
    const float* bias = (L == 0) ? b1 : (L == 1) ? b2 : b3;
    const float* Wsc  = (L == 0) ? Ws1 : (L == 1) ? Ws2 : Ws3;
    const float* bscp = (L == 0) ? bs1 : (L == 1) ? bs2 : bs3;
    int K = NPG >> (L + 1);          // 128, 64, 32

    __syncthreads();   // B0: pair writes (or stage/CSR) complete

    // ---- params + dinv (4 waves; concurrent with transform's MFMA start) ----
    if (tid < HF) { bvec[tid] = bias[tid]; wsv[tid] = Wsc[tid]; }
    if (tid < NPG) {
      unsigned mb[8];
      #pragma unroll
      for (int j = 0; j < 8; ++j) mb[j] = mbits[j];
      int e0 = rloc[tid], e1 = rloc[tid+1];
      int c = 0;
      int sA = colS[e0], sB = colS[e0+1];
      for (int e = e0; e < e1; ++e) {
        int s = sA; sA = sB; sB = colS[e+2];
        c += (mb[s>>5] >> (s&31)) & 1;                 // self slot supplies the +1
      }
      bool alive = (mb[tid>>5] >> (tid&31)) & 1;
      dinv[tid] = alive ? (1.0f / sqrtf((float)c)) : 0.0f;
    }

    // ---- transform: G = dinv * (h @ W)  (MFMA on resident bf16 pair, in place) ----
    {
      int rg = wid & 7, cg = wid >> 3;
      int lr = lane & 15, lk8 = (lane >> 4) * 8;
      f32x4 tacc[2][4] = {};
      #pragma unroll
      for (int kc = 0; kc < 4; ++kc) {
        int k0 = kc*32 + lk8;
        bf16x8 ah[2], al[2];
        #pragma unroll
        for (int rt = 0; rt < 2; ++rt) {
          int row = rg*32 + rt*16 + lr;
          ah[rt] = *(const bf16x8*)&hp0[row*PSTR + k0];
          al[rt] = *(const bf16x8*)&hp1[row*PSTR + k0];
        }
        #pragma unroll
        for (int ct = 0; ct < 4; ++ct) {
          int n = cg*64 + ct*16 + lr;
          bf16x8 bh = *(const bf16x8*)&Whi[n*HF + k0];
          bf16x8 bl = *(const bf16x8*)&Wlo[n*HF + k0];
          #pragma unroll
          for (int rt = 0; rt < 2; ++rt) {
            tacc[rt][ct] = __builtin_amdgcn_mfma_f32_16x16x32_bf16(ah[rt], bh, tacc[rt][ct], 0, 0, 0);
            tacc[rt][ct] = __builtin_amdgcn_mfma_f32_16x16x32_bf16(al[rt], bh, tacc[rt][ct], 0, 0, 0);
            tacc[rt][ct] = __builtin_amdgcn_mfma_f32_16x16x32_bf16(ah[rt], bl, tacc[rt][ct], 0, 0, 0);
          }
        }
      }
      __syncthreads();   // B1: all pair reads done (dinv also complete)
      #pragma unroll
      for (int rt = 0; rt < 2; ++rt) {
        int row0 = rg*32 + rt*16 + (lane >> 4)*4;
        float d0 = dinv[row0+0], d1 = dinv[row0+1], d2 = dinv[row0+2], d3 = dinv[row0+3];
        #pragma unroll
        for (int ct = 0; ct < 4; ++ct) {
          int c = cg*64 + ct*16 + (lane & 15);
          tbufF[(row0+0)*FSTR + c] = tacc[rt][ct][0] * d0;
          tbufF[(row0+1)*FSTR + c] = tacc[rt][ct][1] * d1;
          tbufF[(row0+2)*FSTR + c] = tacc[rt][ct][2] * d2;
          tbufF[(row0+3)*FSTR + c] = tacc[rt][ct][3] * d3;
        }
      }
    }
    __syncthreads();   // B2: G ready

    // ---- aggregation: plain sum of G rows over edges (incl self), branchless ----
    float4 hv[8];
    {
      float4 acc[8] = {};
      int e0 = rloc[v], e1 = rloc[v+1];
      int sA = colS[e0], sB = colS[e0+1];
      for (int e = e0; e < e1; ++e) {
        int s = sA; sA = sB; sB = colS[e+2];
        const float* gr = &tbufF[s*FSTR + cb];
        #pragma unroll
        for (int i = 0; i < 8; ++i) {
          float4 t = *(const float4*)&gr[i*16];
          acc[i].x += t.x; acc[i].y += t.y; acc[i].z += t.z; acc[i].w += t.w;
        }
      }
      float dv = dinv[v];
      float p = 0.f;
      #pragma unroll
      for (int i = 0; i < 8; ++i) {
        int ci = i*16 + cb;
        float4 bv = *(const float4*)&bvec[ci];
        float4 wv = *(const float4*)&wsv[ci];
        float4 a;
        a.x = fmaxf(fmaf(dv, acc[i].x, bv.x), 0.f);
        a.y = fmaxf(fmaf(dv, acc[i].y, bv.y), 0.f);
        a.z = fmaxf(fmaf(dv, acc[i].z, bv.z), 0.f);
        a.w = fmaxf(fmaf(dv, acc[i].w, bv.w), 0.f);
        hv[i] = a;
        p += a.x*wv.x + a.y*wv.y + a.z*wv.z + a.w*wv.w;
      }
      red[tid] = p;
    }
    __syncthreads();   // B3: score partials ready, G reads done
    if (tid < NPG) {
      float4 q = *(const float4*)&red[tid*4];
      tscale[tid] = ((q.x + q.y) + (q.z + q.w)) * dinv[tid];   // tq = (h.Ws)*dinv
      nmf[tid] = 0.f;
    }
    __syncthreads();   // B4
    if (tid < NPG) {
      int e0 = rloc[tid], e1 = rloc[tid+1];
      float sa = 0.f;
      int sA = colS[e0], sB = colS[e0+1];
      for (int e = e0; e < e1; ++e) {
        int s = sA; sA = sB; sB = colS[e+2];
        sa += tscale[s];
      }
      score[tid] = dinv[tid] * sa + bscp[0];
    }
    __syncthreads();   // B5: scores ready

    // ---- register bitonic top-K (4 waves), desc score / asc idx ----
    float kf = -INFINITY; int ki = tid;
    if (tid < NPG) {
      bool alive = (mbits[tid>>5] >> (tid&31)) & 1;
      kf = alive ? score[tid] : -INFINITY;
      for (int kk = 2; kk <= 64; kk <<= 1)
        for (int j = kk >> 1; j > 0; j >>= 1) {
          float ok = __shfl_xor(kf, j);
          int   oi = __shfl_xor(ki, j);
          BSTEP(ok, oi, kk, j);
        }
    }
    if (tid < NPG) { skey[tid] = kf; sidx[tid] = ki; }
    __syncthreads();
    if (tid < NPG) {
      int l = tid ^ 64; float ok = skey[l]; int oi = sidx[l];
      BSTEP(ok, oi, 128, 64);
      for (int j = 32; j > 0; j >>= 1) {
        float sk = __shfl_xor(kf, j); int si = __shfl_xor(ki, j);
        BSTEP(sk, si, 128, j);
      }
    }
    __syncthreads();
    if (tid < NPG) { skey[tid] = kf; sidx[tid] = ki; }
    __syncthreads();
    if (tid < NPG) {
      int l = tid ^ 128; float ok = skey[l]; int oi = sidx[l];
      BSTEP(ok, oi, 256, 128);
    }
    __syncthreads();
    if (tid < NPG) { skey[tid] = kf; sidx[tid] = ki; }
    __syncthreads();
    if (tid < NPG) {
      int l = tid ^ 64; float ok = skey[l]; int oi = sidx[l];
      BSTEP(ok, oi, 256, 64);
      for (int j = 32; j > 0; j >>= 1) {
        float sk = __shfl_xor(kf, j); int si = __shfl_xor(ki, j);
        BSTEP(sk, si, 256, j);
      }
    }
    __syncthreads();
    if (tid < 8) mbits[tid] = 0u;
    __syncthreads();
    if (tid < K) { nmf[ki] = 1.0f; atomicOr(&mbits[ki>>5], 1u << (ki&31)); }
    __syncthreads();
    if (tid < NPG) tscale[tid] = tanhf(score[tid]) * nmf[tid];
    __syncthreads();

    // ---- scale (regs) + write f32 for readout ----
    {
      float ts = tscale[v];
      #pragma unroll
      for (int i = 0; i < 8; ++i) {
        hv[i].x *= ts; hv[i].y *= ts; hv[i].z *= ts; hv[i].w *= ts;
        *(float4*)&tbufF[v*FSTR + i*16 + cb] = hv[i];
      }
    }
    __syncthreads();

    // ---- readout: max & mean over selected nodes -> zacc ----
    {
      int f = tid & 127, vg = tid >> 7;
      float mx = -INFINITY, sm = 0.f;
      for (int vr = 0; vr < 32; ++vr) {
        int vv = vg*32 + vr;
        float val = tbufF[vv*FSTR + f];
        if (nmf[vv] > 0.f) { mx = fmaxf(mx, val); sm += val; }
      }
      red[vg*HF + f] = mx;
      __syncthreads();
      if (tid < HF) {
        float zm = red[tid];
        #pragma unroll
        for (int q = 1; q < 8; ++q) zm = fmaxf(zm, red[q*HF + tid]);
        if (L == 0) zacc[tid] = zm; else zacc[tid] += zm;
      }
      __syncthreads();
      red[vg*HF + f] = sm;
      __syncthreads();
      if (tid < HF) {
        float zs = red[tid];
        #pragma unroll
        for (int q = 1; q < 8; ++q) zs += red[q*HF + tid];
        float mn = zs / (float)K;
        if (L == 0) zacc[HF + tid] = mn; else zacc[HF + tid] += mn;
      }
      __syncthreads();   // all tbufF/red reads done
    }

    // ---- pack scaled h into bf16 pair for next layer ----
    if (L < 2) {
      #pragma unroll
      for (int i = 0; i < 8; ++i) {
        int ci = i*16 + cb;
        float4 val = hv[i];
        unsigned rx = rtn16(val.x), ry = rtn16(val.y), rz = rtn16(val.z), rw = rtn16(val.w);
        uint2 ph; ph.x = rx | (ry << 16); ph.y = rz | (rw << 16);
        float lx = val.x - bcf(rx << 16), ly = val.y - bcf(ry << 16);
        float lz = val.z - bcf(rz << 16), lw = val.w - bcf(rw << 16);
        uint2 pl; pl.x = (bcu(lx) >> 16) | (bcu(ly) & 0xFFFF0000u);
        pl.y = (bcu(lz) >> 16) | (bcu(lw) & 0xFFFF0000u);
        *(uint2*)&hp0[v*PSTR + ci] = ph;
        *(uint2*)&hp1[v*PSTR + ci] = pl;
      }
    }
  }

  __syncthreads();

  // ---- MLP head + log_softmax ----
  {
    int o = tid & 127, kg = tid >> 7;
    float p = 0.f;
    int k0 = kg*32;
    for (int k = k0; k < k0+32; ++k) p += zacc[k]*Wl1[k*HF + o];
    red[kg*HF + o] = p;
    __syncthreads();
    if (tid < HF) {
      float a = bl1[tid];
      #pragma unroll
      for (int q = 0; q < 8; ++q) a += red[q*HF + tid];
      score[tid] = fmaxf(a, 0.f);       // h1
    }
    __syncthreads();
    if (tid < 512) {
      int o2 = tid & 63, kg2 = tid >> 6;
      float p2 = 0.f;
      int k0b = kg2*16;
      for (int k = k0b; k < k0b+16; ++k) p2 += score[k]*Wl2[k*64 + o2];
      red[kg2*64 + o2] = p2;
    }
    __syncthreads();
    if (tid < 64) {
      float a = bl2[tid];
      #pragma unroll
      for (int q = 0; q < 8; ++q) a += red[q*64 + tid];
      tscale[tid] = fmaxf(a, 0.f);      // h2
    }
    __syncthreads();
    if (tid < 10) {
      float a = bl3[tid];
      for (int k = 0; k < 64; ++k) a += tscale[k]*Wl3[k*10 + tid];
      nmf[tid] = fmaxf(a, 0.f);         // logits
    }
    __syncthreads();
    if (tid == 0) {
      float m = nmf[0];
      for (int i = 1; i < 10; ++i) m = fmaxf(m, nmf[i]);
      float s = 0.f;
      for (int i = 0; i < 10; ++i) s += expf(nmf[i] - m);
      red[0] = m; red[1] = logf(s);
    }
    __syncthreads();
    if (tid < 10) out[(size_t)g*10 + tid] = nmf[tid] - red[0] - red[1];
  }
}

extern "C" void kernel_launch(void* const* d_in, const int* in_sizes, int n_in,
                              void* d_out, int out_size, void* d_ws, size_t ws_size,
                              hipStream_t stream) {
  const float* x   = (const float*)d_in[0];
  const int*  srcI = (const int*)d_in[1];
  const int*  dstI = (const int*)d_in[2];
  const float* W1  = (const float*)d_in[3];
  const float* b1  = (const float*)d_in[4];
  const float* W2  = (const float*)d_in[5];
  const float* b2  = (const float*)d_in[6];
  const float* W3  = (const float*)d_in[7];
  const float* b3  = (const float*)d_in[8];
  const float* Ws1 = (const float*)d_in[9];
  const float* bs1 = (const float*)d_in[10];
  const float* Ws2 = (const float*)d_in[11];
  const float* bs2 = (const float*)d_in[12];
  const float* Ws3 = (const float*)d_in[13];
  const float* bs3 = (const float*)d_in[14];
  const float* Wl1 = (const float*)d_in[15];
  const float* bl1 = (const float*)d_in[16];
  const float* Wl2 = (const float*)d_in[17];
  const float* bl2 = (const float*)d_in[18];
  const float* Wl3 = (const float*)d_in[19];
  const float* bl3 = (const float*)d_in[20];
  float* out = (float*)d_out;

  short* WtAll = (short*)d_ws;   // 3 * 2 * 16384 shorts = 192 KB

  prep_wt<<<192, 256, 0, stream>>>(W1, W2, W3, WtAll);
  fused_net<<<NGRAPH, 1024, 0, stream>>>(x, srcI, dstI, WtAll,
                                         b1, Ws1, bs1, b2, Ws2, bs2, b3, Ws3, bs3,
                                         Wl1, bl1, Wl2, bl2, Wl3, bl3, out);
}

// Round 6
// 135.315 us; speedup vs baseline: 1.0809x; 1.0809x over previous
//
#include <hip/hip_runtime.h>
#include <math.h>

#define NGRAPH 256
#define NPG 256
#define HF 128
#define EPG 4096      // real edges per graph (global arrays)
#define EPG2 4352     // max CSR slots incl one self-edge per node
#define FSTR 132      // f32 row stride in tbufF (aliases hpair)
#define PSTR 136      // short row stride in hpair (16B-aligned rows)

typedef __attribute__((ext_vector_type(8))) short bf16x8;
typedef __attribute__((ext_vector_type(4))) float f32x4;

static __device__ __forceinline__ unsigned bcu(float f){ return __builtin_bit_cast(unsigned, f); }
static __device__ __forceinline__ float bcf(unsigned u){ return __builtin_bit_cast(float, u); }
static __device__ __forceinline__ unsigned rtn16(float f){
  unsigned u = bcu(f);
  return (u + 0x7FFFu + ((u >> 16) & 1u)) >> 16;
}

// ---------------- W transpose + split to bf16 hi/lo: Wt[n][k] ----------------
__global__ __launch_bounds__(256) void prep_wt(const float* __restrict__ W1,
                                               const float* __restrict__ W2,
                                               const float* __restrict__ W3,
                                               short* __restrict__ Wt) {
  int idx = blockIdx.x * 256 + threadIdx.x;           // 0 .. 3*16384
  int L = idx >> 14, r = idx & 16383;
  int k = r >> 7, n = r & 127;
  const float* W = (L == 0) ? W1 : (L == 1) ? W2 : W3;
  float w = W[k*128 + n];
  unsigned hi = rtn16(w);
  float lo = w - bcf(hi << 16);
  short* Whi = Wt + (size_t)L * 2 * 16384;
  short* Wlo = Whi + 16384;
  Whi[n*128 + k] = (short)hi;
  Wlo[n*128 + k] = (short)(bcu(lo) >> 16);
}

// sort compare-exchange step (descending key, ascending idx on ties)
#define BSTEP(OK, OI, KKc, Jc) do { \
  bool iLess = ((tid & (Jc)) == 0); \
  bool descR = ((tid & (KKc)) == 0); \
  bool myFirst = (kf > (OK)) || (kf == (OK) && ki < (OI)); \
  bool keep = (iLess == descR) ? myFirst : !myFirst; \
  if (!keep) { kf = (OK); ki = (OI); } \
} while (0)

// ---------------- whole network, one block per graph ----------------
__global__ __launch_bounds__(1024) void fused_net(
    const float* __restrict__ x,
    const int* __restrict__ srcI, const int* __restrict__ dstI,
    const short* __restrict__ WtAll,
    const float* __restrict__ b1, const float* __restrict__ Ws1, const float* __restrict__ bs1,
    const float* __restrict__ b2, const float* __restrict__ Ws2, const float* __restrict__ bs2,
    const float* __restrict__ b3, const float* __restrict__ Ws3, const float* __restrict__ bs3,
    const float* __restrict__ Wl1, const float* __restrict__ bl1,
    const float* __restrict__ Wl2, const float* __restrict__ bl2,
    const float* __restrict__ Wl3, const float* __restrict__ bl3,
    float* __restrict__ out)
{
  __shared__ __align__(16) short hpair[2][NPG*PSTR];   // 139264 B; aliased by tbufF
  __shared__ unsigned char colS[EPG2 + 8];             // compacted CSR col, by dst, incl self
  __shared__ unsigned short rloc[NPG+2];
  __shared__ unsigned mbits[8];                        // survivor bitmask
  __shared__ float dinv[NPG];
  __shared__ __align__(16) float bvec[HF];
  __shared__ __align__(16) float wsv[HF];
  __shared__ float score[NPG];
  __shared__ float tscale[NPG];                        // tq scratch / tanh scale
  __shared__ float nmf[NPG];
  __shared__ float skey[NPG];
  __shared__ int   sidx[NPG];
  __shared__ __align__(16) float red[1024];            // partials / readout / MLP scratch
  __shared__ float zacc[2*HF];

  float* tbufF = (float*)&hpair[0][0];                 // [node][FSTR] f32 (G rows), alias
  short* hp0 = &hpair[0][0];
  short* hp1 = &hpair[1][0];
  int* cntA = (int*)skey;                              // CSR-build aliases (sort idle)
  int* curA = sidx;

  int tid = threadIdx.x;
  int g = blockIdx.x;
  size_t nbase = (size_t)g * NPG;
  int lane = tid & 63, wid = tid >> 6;
  int v = tid >> 2, fq = tid & 3, cb = fq * 4;

  // ---- stage x into bf16 hi/lo pair ----
  const float4* X4 = (const float4*)(x + nbase*HF);
  #pragma unroll
  for (int i = 0; i < 8; ++i) {
    int f4 = tid + i*1024;
    int r = f4 >> 5, kq = f4 & 31;
    float4 val = X4[f4];
    unsigned rx = rtn16(val.x), ry = rtn16(val.y), rz = rtn16(val.z), rw = rtn16(val.w);
    uint2 ph; ph.x = rx | (ry << 16); ph.y = rz | (rw << 16);
    float lx = val.x - bcf(rx << 16), ly = val.y - bcf(ry << 16);
    float lz = val.z - bcf(rz << 16), lw = val.w - bcf(rw << 16);
    uint2 pl; pl.x = (bcu(lx) >> 16) | (bcu(ly) & 0xFFFF0000u);
    pl.y = (bcu(lz) >> 16) | (bcu(lw) & 0xFFFF0000u);
    *(uint2*)&hp0[r*PSTR + kq*4] = ph;
    *(uint2*)&hp1[r*PSTR + kq*4] = pl;
  }

  // ---- edges into registers (kept all layers) ----
  int nb = g * NPG;
  int dloc[4], sloc[4];
  #pragma unroll
  for (int it = 0; it < 4; ++it) {
    int e = g*EPG + tid + it*1024;
    dloc[it] = dstI[e] - nb;
    sloc[it] = srcI[e] - nb;
  }

  // ---- initial CSR build (all nodes alive, +1 self slot per node) ----
  if (tid < NPG) cntA[tid] = 1;
  if (tid < 8) mbits[tid] = 0xFFFFFFFFu;
  __syncthreads();
  #pragma unroll
  for (int it = 0; it < 4; ++it) atomicAdd(&cntA[dloc[it]], 1);
  __syncthreads();
  if (tid < NPG) sidx[tid] = cntA[tid];
  __syncthreads();
  for (int off = 1; off < NPG; off <<= 1) {
    int t = (tid >= off && tid < NPG) ? sidx[tid-off] : 0;
    __syncthreads();
    if (tid < NPG) sidx[tid] += t;
    __syncthreads();
  }
  int excl_ = 0;
  if (tid < NPG) excl_ = sidx[tid] - cntA[tid];
  __syncthreads();
  if (tid < NPG) { rloc[tid] = (unsigned short)excl_; curA[tid] = excl_; }
  if (tid == 0) rloc[NPG] = (unsigned short)EPG2;
  __syncthreads();
  #pragma unroll
  for (int it = 0; it < 4; ++it) {
    int slot = atomicAdd(&curA[dloc[it]], 1);
    colS[slot] = (unsigned char)sloc[it];
  }
  if (tid < NPG) colS[rloc[tid+1] - 1] = (unsigned char)tid;  // self in last slot

  // ---- 3 GCN+SAGPool layers ----
  #pragma unroll 1
  for (int L = 0; L < 3; ++L) {
    const short* Whi = WtAll + (size_t)L * 2 * 16384;
    const short* Wlo = Whi + 16384;
    const float* bias = (L == 0) ? b1 : (L == 1) ? b2 : b3;
    const float* Wsc  = (L == 0) ? Ws1 : (L == 1) ? Ws2 : Ws3;
    const float* bscp = (L == 0) ? bs1 : (L == 1) ? bs2 : bs3;
    int K = NPG >> (L + 1);          // 128, 64, 32

    __syncthreads();   // B0: pair writes + CSR (re)build complete

    // ---- params + dinv (compacted row length IS the degree incl self) ----
    if (tid < HF) { bvec[tid] = bias[tid]; wsv[tid] = Wsc[tid]; }
    if (tid < NPG) {
      int c = (int)rloc[tid+1] - (int)rloc[tid];
      bool alive = (mbits[tid>>5] >> (tid&31)) & 1;
      dinv[tid] = alive ? (1.0f / sqrtf((float)c)) : 0.0f;
    }

    // ---- transform: G = dinv * (h @ W)  (MFMA on resident bf16 pair, in place) ----
    {
      int rg = wid & 7, cg = wid >> 3;
      int lr = lane & 15, lk8 = (lane >> 4) * 8;
      f32x4 tacc[2][4] = {};
      #pragma unroll
      for (int kc = 0; kc < 4; ++kc) {
        int k0 = kc*32 + lk8;
        bf16x8 ah[2], al[2];
        #pragma unroll
        for (int rt = 0; rt < 2; ++rt) {
          int row = rg*32 + rt*16 + lr;
          ah[rt] = *(const bf16x8*)&hp0[row*PSTR + k0];
          al[rt] = *(const bf16x8*)&hp1[row*PSTR + k0];
        }
        #pragma unroll
        for (int ct = 0; ct < 4; ++ct) {
          int n = cg*64 + ct*16 + lr;
          bf16x8 bh = *(const bf16x8*)&Whi[n*HF + k0];
          bf16x8 bl = *(const bf16x8*)&Wlo[n*HF + k0];
          #pragma unroll
          for (int rt = 0; rt < 2; ++rt) {
            tacc[rt][ct] = __builtin_amdgcn_mfma_f32_16x16x32_bf16(ah[rt], bh, tacc[rt][ct], 0, 0, 0);
            tacc[rt][ct] = __builtin_amdgcn_mfma_f32_16x16x32_bf16(al[rt], bh, tacc[rt][ct], 0, 0, 0);
            tacc[rt][ct] = __builtin_amdgcn_mfma_f32_16x16x32_bf16(ah[rt], bl, tacc[rt][ct], 0, 0, 0);
          }
        }
      }
      __syncthreads();   // B1: all pair reads done (dinv also complete)
      #pragma unroll
      for (int rt = 0; rt < 2; ++rt) {
        int row0 = rg*32 + rt*16 + (lane >> 4)*4;
        float d0 = dinv[row0+0], d1 = dinv[row0+1], d2 = dinv[row0+2], d3 = dinv[row0+3];
        #pragma unroll
        for (int ct = 0; ct < 4; ++ct) {
          int c = cg*64 + ct*16 + (lane & 15);
          tbufF[(row0+0)*FSTR + c] = tacc[rt][ct][0] * d0;
          tbufF[(row0+1)*FSTR + c] = tacc[rt][ct][1] * d1;
          tbufF[(row0+2)*FSTR + c] = tacc[rt][ct][2] * d2;
          tbufF[(row0+3)*FSTR + c] = tacc[rt][ct][3] * d3;
        }
      }
    }
    __syncthreads();   // B2: G ready

    // ---- aggregation: plain sum of G rows over compacted edges (incl self) ----
    float4 hv[8];
    {
      float4 acc[8] = {};
      int e0 = rloc[v], e1 = rloc[v+1];
      int sA = colS[e0], sB = colS[e0+1];
      for (int e = e0; e < e1; ++e) {
        int s = sA; sA = sB; sB = colS[e+2];
        const float* gr = &tbufF[s*FSTR + cb];
        #pragma unroll
        for (int i = 0; i < 8; ++i) {
          float4 t = *(const float4*)&gr[i*16];
          acc[i].x += t.x; acc[i].y += t.y; acc[i].z += t.z; acc[i].w += t.w;
        }
      }
      float dv = dinv[v];
      float p = 0.f;
      #pragma unroll
      for (int i = 0; i < 8; ++i) {
        int ci = i*16 + cb;
        float4 bv = *(const float4*)&bvec[ci];
        float4 wv = *(const float4*)&wsv[ci];
        float4 a;
        a.x = fmaxf(fmaf(dv, acc[i].x, bv.x), 0.f);
        a.y = fmaxf(fmaf(dv, acc[i].y, bv.y), 0.f);
        a.z = fmaxf(fmaf(dv, acc[i].z, bv.z), 0.f);
        a.w = fmaxf(fmaf(dv, acc[i].w, bv.w), 0.f);
        hv[i] = a;
        p += a.x*wv.x + a.y*wv.y + a.z*wv.z + a.w*wv.w;
      }
      red[tid] = p;
    }
    __syncthreads();   // B3: score partials ready, G reads done
    if (tid < NPG) {
      float4 q = *(const float4*)&red[tid*4];
      tscale[tid] = ((q.x + q.y) + (q.z + q.w)) * dinv[tid];   // tq = (h.Ws)*dinv
      nmf[tid] = 0.f;
    }
    __syncthreads();   // B4
    if (tid < NPG) {
      int e0 = rloc[tid], e1 = rloc[tid+1];
      float sa = 0.f;
      int sA = colS[e0], sB = colS[e0+1];
      for (int e = e0; e < e1; ++e) {
        int s = sA; sA = sB; sB = colS[e+2];
        sa += tscale[s];
      }
      score[tid] = dinv[tid] * sa + bscp[0];
    }
    __syncthreads();   // B5: scores ready

    // ---- register bitonic top-K (4 waves), desc score / asc idx ----
    float kf = -INFINITY; int ki = tid;
    if (tid < NPG) {
      bool alive = (mbits[tid>>5] >> (tid&31)) & 1;
      kf = alive ? score[tid] : -INFINITY;
      for (int kk = 2; kk <= 64; kk <<= 1)
        for (int j = kk >> 1; j > 0; j >>= 1) {
          float ok = __shfl_xor(kf, j);
          int   oi = __shfl_xor(ki, j);
          BSTEP(ok, oi, kk, j);
        }
    }
    if (tid < NPG) { skey[tid] = kf; sidx[tid] = ki; }
    __syncthreads();
    if (tid < NPG) {
      int l = tid ^ 64; float ok = skey[l]; int oi = sidx[l];
      BSTEP(ok, oi, 128, 64);
      for (int j = 32; j > 0; j >>= 1) {
        float sk = __shfl_xor(kf, j); int si = __shfl_xor(ki, j);
        BSTEP(sk, si, 128, j);
      }
    }
    __syncthreads();
    if (tid < NPG) { skey[tid] = kf; sidx[tid] = ki; }
    __syncthreads();
    if (tid < NPG) {
      int l = tid ^ 128; float ok = skey[l]; int oi = sidx[l];
      BSTEP(ok, oi, 256, 128);
    }
    __syncthreads();
    if (tid < NPG) { skey[tid] = kf; sidx[tid] = ki; }
    __syncthreads();
    if (tid < NPG) {
      int l = tid ^ 64; float ok = skey[l]; int oi = sidx[l];
      BSTEP(ok, oi, 256, 64);
      for (int j = 32; j > 0; j >>= 1) {
        float sk = __shfl_xor(kf, j); int si = __shfl_xor(ki, j);
        BSTEP(sk, si, 256, j);
      }
    }
    __syncthreads();
    if (tid < 8) mbits[tid] = 0u;
    __syncthreads();
    if (tid < K) { nmf[ki] = 1.0f; atomicOr(&mbits[ki>>5], 1u << (ki&31)); }
    __syncthreads();
    if (tid < NPG) tscale[tid] = tanhf(score[tid]) * nmf[tid];
    __syncthreads();

    // ---- scale (regs) + write f32 for readout ----
    {
      float ts = tscale[v];
      #pragma unroll
      for (int i = 0; i < 8; ++i) {
        hv[i].x *= ts; hv[i].y *= ts; hv[i].z *= ts; hv[i].w *= ts;
        *(float4*)&tbufF[v*FSTR + i*16 + cb] = hv[i];
      }
    }
    __syncthreads();

    // ---- readout: max & mean over selected nodes -> zacc ----
    {
      int f = tid & 127, vg = tid >> 7;
      float mx = -INFINITY, sm = 0.f;
      for (int vr = 0; vr < 32; ++vr) {
        int vv = vg*32 + vr;
        float val = tbufF[vv*FSTR + f];
        if (nmf[vv] > 0.f) { mx = fmaxf(mx, val); sm += val; }
      }
      red[vg*HF + f] = mx;
      __syncthreads();
      if (tid < HF) {
        float zm = red[tid];
        #pragma unroll
        for (int q = 1; q < 8; ++q) zm = fmaxf(zm, red[q*HF + tid]);
        if (L == 0) zacc[tid] = zm; else zacc[tid] += zm;
      }
      __syncthreads();
      red[vg*HF + f] = sm;
      __syncthreads();
      if (tid < HF) {
        float zs = red[tid];
        #pragma unroll
        for (int q = 1; q < 8; ++q) zs += red[q*HF + tid];
        float mn = zs / (float)K;
        if (L == 0) zacc[HF + tid] = mn; else zacc[HF + tid] += mn;
      }
      __syncthreads();   // all tbufF/red reads done
    }

    if (L < 2) {
      // ---- pack scaled h into bf16 pair for next layer ----
      #pragma unroll
      for (int i = 0; i < 8; ++i) {
        int ci = i*16 + cb;
        float4 val = hv[i];
        unsigned rx = rtn16(val.x), ry = rtn16(val.y), rz = rtn16(val.z), rw = rtn16(val.w);
        uint2 ph; ph.x = rx | (ry << 16); ph.y = rz | (rw << 16);
        float lx = val.x - bcf(rx << 16), ly = val.y - bcf(ry << 16);
        float lz = val.z - bcf(rz << 16), lw = val.w - bcf(rw << 16);
        uint2 pl; pl.x = (bcu(lx) >> 16) | (bcu(ly) & 0xFFFF0000u);
        pl.y = (bcu(lz) >> 16) | (bcu(lw) & 0xFFFF0000u);
        *(uint2*)&hp0[v*PSTR + ci] = ph;
        *(uint2*)&hp1[v*PSTR + ci] = pl;
      }

      // ---- rebuild compacted CSR for the new mask (both endpoints alive) ----
      bool keep[4];
      #pragma unroll
      for (int it = 0; it < 4; ++it) {
        keep[it] = (((mbits[dloc[it]>>5] >> (dloc[it]&31)) & 1) &
                    ((mbits[sloc[it]>>5] >> (sloc[it]&31)) & 1)) != 0;
      }
      bool aliveMe = false;
      if (tid < NPG) aliveMe = (mbits[tid>>5] >> (tid&31)) & 1;
      __syncthreads();               // mbits reads done; cntA/curA (skey/sidx) free
      if (tid < NPG) cntA[tid] = aliveMe ? 1 : 0;
      __syncthreads();
      #pragma unroll
      for (int it = 0; it < 4; ++it)
        if (keep[it]) atomicAdd(&cntA[dloc[it]], 1);
      __syncthreads();
      if (tid < NPG) sidx[tid] = cntA[tid];
      __syncthreads();
      for (int off = 1; off < NPG; off <<= 1) {
        int t = (tid >= off && tid < NPG) ? sidx[tid-off] : 0;
        __syncthreads();
        if (tid < NPG) sidx[tid] += t;
        __syncthreads();
      }
      int ex2 = 0, tot2 = 0;
      if (tid < NPG) { ex2 = sidx[tid] - cntA[tid]; }
      if (tid == NPG-1) tot2 = sidx[NPG-1];
      __syncthreads();
      if (tid < NPG) { rloc[tid] = (unsigned short)ex2; curA[tid] = ex2; }
      if (tid == NPG-1) rloc[NPG] = (unsigned short)tot2;
      __syncthreads();
      #pragma unroll
      for (int it = 0; it < 4; ++it) {
        if (keep[it]) {
          int slot = atomicAdd(&curA[dloc[it]], 1);
          colS[slot] = (unsigned char)sloc[it];
        }
      }
      if (tid < NPG && aliveMe) colS[rloc[tid+1] - 1] = (unsigned char)tid;
      // B0 at top of next layer iteration covers completion
    }
  }

  __syncthreads();

  // ---- MLP head + log_softmax ----
  {
    int o = tid & 127, kg = tid >> 7;
    float p = 0.f;
    int k0 = kg*32;
    for (int k = k0; k < k0+32; ++k) p += zacc[k]*Wl1[k*HF + o];
    red[kg*HF + o] = p;
    __syncthreads();
    if (tid < HF) {
      float a = bl1[tid];
      #pragma unroll
      for (int q = 0; q < 8; ++q) a += red[q*HF + tid];
      score[tid] = fmaxf(a, 0.f);       // h1
    }
    __syncthreads();
    if (tid < 512) {
      int o2 = tid & 63, kg2 = tid >> 6;
      float p2 = 0.f;
      int k0b = kg2*16;
      for (int k = k0b; k < k0b+16; ++k) p2 += score[k]*Wl2[k*64 + o2];
      red[kg2*64 + o2] = p2;
    }
    __syncthreads();
    if (tid < 64) {
      float a = bl2[tid];
      #pragma unroll
      for (int q = 0; q < 8; ++q) a += red[q*64 + tid];
      tscale[tid] = fmaxf(a, 0.f);      // h2
    }
    __syncthreads();
    if (tid < 10) {
      float a = bl3[tid];
      for (int k = 0; k < 64; ++k) a += tscale[k]*Wl3[k*10 + tid];
      nmf[tid] = fmaxf(a, 0.f);         // logits
    }
    __syncthreads();
    if (tid == 0) {
      float m = nmf[0];
      for (int i = 1; i < 10; ++i) m = fmaxf(m, nmf[i]);
      float s = 0.f;
      for (int i = 0; i < 10; ++i) s += expf(nmf[i] - m);
      red[0] = m; red[1] = logf(s);
    }
    __syncthreads();
    if (tid < 10) out[(size_t)g*10 + tid] = nmf[tid] - red[0] - red[1];
  }
}

extern "C" void kernel_launch(void* const* d_in, const int* in_sizes, int n_in,
                              void* d_out, int out_size, void* d_ws, size_t ws_size,
                              hipStream_t stream) {
  const float* x   = (const float*)d_in[0];
  const int*  srcI = (const int*)d_in[1];
  const int*  dstI = (const int*)d_in[2];
  const float* W1  = (const float*)d_in[3];
  const float* b1  = (const float*)d_in[4];
  const float* W2  = (const float*)d_in[5];
  const float* b2  = (const float*)d_in[6];
  const float* W3  = (const float*)d_in[7];
  const float* b3  = (const float*)d_in[8];
  const float* Ws1 = (const float*)d_in[9];
  const float* bs1 = (const float*)d_in[10];
  const float* Ws2 = (const float*)d_in[11];
  const float* bs2 = (const float*)d_in[12];
  const float* Ws3 = (const float*)d_in[13];
  const float* bs3 = (const float*)d_in[14];
  const float* Wl1 = (const float*)d_in[15];
  const float* bl1 = (const float*)d_in[16];
  const float* Wl2 = (const float*)d_in[17];
  const float* bl2 = (const float*)d_in[18];
  const float* Wl3 = (const float*)d_in[19];
  const float* bl3 = (const float*)d_in[20];
  float* out = (float*)d_out;

  short* WtAll = (short*)d_ws;   // 3 * 2 * 16384 shorts = 192 KB

  prep_wt<<<192, 256, 0, stream>>>(W1, W2, W3, WtAll);
  fused_net<<<NGRAPH, 1024, 0, stream>>>(x, srcI, dstI, WtAll,
                                         b1, Ws1, bs1, b2, Ws2, bs2, b3, Ws3, bs3,
                                         Wl1, bl1, Wl2, bl2, Wl3, bl3, out);
}